// Round 10
// baseline (160.961 us; speedup 1.0000x reference)
//
#include <hip/hip_runtime.h>
#include <cstdint>
#include <cstddef>

#define B_    4
#define C_    64
#define N_    4096   // 64*64
#define FPD_  128
// fold (1/sqrt(64)) * log2(e) into stored Q so attn does pv = exp2(s)
#define QSCALE_ (0.125f * 1.4426950408889634f)

#if __has_builtin(__builtin_amdgcn_exp2f)
#define EXP2(x) __builtin_amdgcn_exp2f(x)
#else
#define EXP2(x) exp2f(x)
#endif

typedef short bf16x8 __attribute__((ext_vector_type(8)));
typedef float f32x4  __attribute__((ext_vector_type(4)));

__device__ inline unsigned short f2bf(float f) {
    union { float f; unsigned int u; } v; v.f = f;
    unsigned int u = v.u;
    return (unsigned short)((u + 0x7FFFu + ((u >> 16) & 1u)) >> 16);  // RNE
}
__device__ inline unsigned int pack2bf(float a, float b) {
    return (unsigned int)f2bf(a) | ((unsigned int)f2bf(b) << 16);
}
// round-half-up bf16 (2 ops); differs from RNE only on exact ties
__device__ inline unsigned short f2bf_fast(float f) {
    union { float f; unsigned int u; } v; v.f = f;
    return (unsigned short)((v.u + 0x8000u) >> 16);
}
__device__ inline unsigned int pack2bf_fast(float a, float b) {
    union { float f; unsigned int u; } ua, ub; ua.f = a; ub.f = b;
    return ((ua.u + 0x8000u) >> 16) | ((ub.u + 0x8000u) & 0xFFFF0000u);
}
__device__ inline float bflo(unsigned int u) {
    union { unsigned int u; float f; } v; v.u = u << 16; return v.f;
}
__device__ inline float bfhi(unsigned int u) {
    union { unsigned int u; float f; } v; v.u = u & 0xFFFF0000u; return v.f;
}

// ---------------------------------------------------------------- kernel 1
// Fused prep+QKV. Grid 768: pass = bx>>8 (0=Q,1=K,2=V), rem = bx&255 ->
// (b, 64-position tile). Pass 0 also computes fp_proj in-block and the gate.
__global__ __launch_bounds__(256) void qkv_kernel(
    const float* __restrict__ x,
    const float* __restrict__ Wq, const float* __restrict__ bq,
    const float* __restrict__ Wk, const float* __restrict__ bk,
    const float* __restrict__ Wv, const float* __restrict__ bv,
    const float* __restrict__ fp, const float* __restrict__ Wfp,
    const float* __restrict__ bfp,
    float* __restrict__ gate,
    unsigned short* __restrict__ Qb, unsigned short* __restrict__ Kb,
    unsigned short* __restrict__ Vb)
{
    __shared__ unsigned short xT[64 * 72];   // [p][c] bf16
    __shared__ unsigned short Wl[64 * 72];   // [o][c] bf16
    __shared__ unsigned short rp[64 * 72];   // repack
    __shared__ float gredf[256];
    __shared__ float fpp[64];

    int tid  = threadIdx.x;
    int bx   = blockIdx.x;
    int pass = bx >> 8;
    int rem  = bx & 255;
    int b  = rem >> 6;
    int p0 = (rem & 63) << 6;
    const float* xb = x + (size_t)b * (C_ * N_) + p0;

    const float* Wsrc = (pass == 0) ? Wq : (pass == 1) ? Wk : Wv;
    const float* bsrc = (pass == 0) ? bq : (pass == 1) ? bk : bv;
    float wscale = (pass == 0) ? QSCALE_ : 1.0f;

    {   // stage W bf16
        int o  = tid >> 2;
        int cb = (tid & 3) << 4;
        const float4* src = reinterpret_cast<const float4*>(&Wsrc[o * 64 + cb]);
        float4 w0 = src[0], w1 = src[1], w2 = src[2], w3 = src[3];
        uint4 lo, hi;
        lo.x = pack2bf(w0.x * wscale, w0.y * wscale);
        lo.y = pack2bf(w0.z * wscale, w0.w * wscale);
        lo.z = pack2bf(w1.x * wscale, w1.y * wscale);
        lo.w = pack2bf(w1.z * wscale, w1.w * wscale);
        hi.x = pack2bf(w2.x * wscale, w2.y * wscale);
        hi.y = pack2bf(w2.z * wscale, w2.w * wscale);
        hi.z = pack2bf(w3.x * wscale, w3.y * wscale);
        hi.w = pack2bf(w3.z * wscale, w3.w * wscale);
        *reinterpret_cast<uint4*>(&Wl[o * 72 + cb])     = lo;
        *reinterpret_cast<uint4*>(&Wl[o * 72 + cb + 8]) = hi;
    }
    // stage x tile transposed [p][c] bf16 — float4 loads (4 p of one c)
    #pragma unroll
    for (int i = 0; i < 4; ++i) {
        int u = tid + i * 256;               // 1024 units
        int c = u >> 4, p4 = (u & 15) << 2;
        float4 v = *reinterpret_cast<const float4*>(&xb[(size_t)c * N_ + p4]);
        xT[(p4 + 0) * 72 + c] = f2bf(v.x);
        xT[(p4 + 1) * 72 + c] = f2bf(v.y);
        xT[(p4 + 2) * 72 + c] = f2bf(v.z);
        xT[(p4 + 3) * 72 + c] = f2bf(v.w);
    }
    if (pass == 0) {                         // fp_proj
        int d = tid >> 2, kq = tid & 3;
        const float4* wrow = reinterpret_cast<const float4*>(&Wfp[d * FPD_ + kq * 32]);
        const float4* frow = reinterpret_cast<const float4*>(&fp[b * FPD_ + kq * 32]);
        float s = 0.f;
        #pragma unroll
        for (int i = 0; i < 8; ++i) {
            float4 w4 = wrow[i], f4 = frow[i];
            s += w4.x * f4.x + w4.y * f4.y + w4.z * f4.z + w4.w * f4.w;
        }
        gredf[tid] = s;
    }
    __syncthreads();
    if (pass == 0 && tid < 64)
        fpp[tid] = bfp[tid] + gredf[tid * 4] + gredf[tid * 4 + 1]
                 + gredf[tid * 4 + 2] + gredf[tid * 4 + 3];
    if (pass == 0) __syncthreads();

    int lane = tid & 63;
    int wv   = __builtin_amdgcn_readfirstlane(tid >> 6);
    int quad = lane >> 4, l16 = lane & 15;
    int prow = wv * 16 + l16;

    bf16x8 bx0 = *reinterpret_cast<bf16x8*>(&xT[prow * 72 + quad * 8]);
    bf16x8 bx1 = *reinterpret_cast<bf16x8*>(&xT[prow * 72 + 32 + quad * 8]);

    float gp = 0.f;
    #pragma unroll
    for (int t4 = 0; t4 < 4; ++t4) {
        bf16x8 a0 = *reinterpret_cast<bf16x8*>(&Wl[(t4 * 16 + l16) * 72 + quad * 8]);
        bf16x8 a1 = *reinterpret_cast<bf16x8*>(&Wl[(t4 * 16 + l16) * 72 + 32 + quad * 8]);
        f32x4 c4 = (f32x4){0.f, 0.f, 0.f, 0.f};
        c4 = __builtin_amdgcn_mfma_f32_16x16x32_bf16(a0, bx0, c4, 0, 0, 0);
        c4 = __builtin_amdgcn_mfma_f32_16x16x32_bf16(a1, bx1, c4, 0, 0, 0);
        float4 bias = *reinterpret_cast<const float4*>(&bsrc[t4 * 16 + quad * 4]);
        c4[0] += bias.x * wscale; c4[1] += bias.y * wscale;
        c4[2] += bias.z * wscale; c4[3] += bias.w * wscale;
        if (pass == 0) {
            gp = fmaf(c4[0], fpp[t4 * 16 + quad * 4 + 0], gp);
            gp = fmaf(c4[1], fpp[t4 * 16 + quad * 4 + 1], gp);
            gp = fmaf(c4[2], fpp[t4 * 16 + quad * 4 + 2], gp);
            gp = fmaf(c4[3], fpp[t4 * 16 + quad * 4 + 3], gp);
        }
        if (pass < 2) {
            int dd = t4 * 16 + quad * 4;
            *reinterpret_cast<ushort2*>(&rp[prow * 72 + dd]) =
                (ushort2){f2bf(c4[0]), f2bf(c4[1])};
            *reinterpret_cast<ushort2*>(&rp[prow * 72 + dd + 2]) =
                (ushort2){f2bf(c4[2]), f2bf(c4[3])};
        } else {
            #pragma unroll
            for (int j = 0; j < 4; ++j)
                rp[(t4 * 16 + quad * 4 + j) * 72 + prow] = f2bf(c4[j]);
        }
    }
    if (pass == 0) {
        gp += __shfl_xor(gp, 16);
        gp += __shfl_xor(gp, 32);
        if (lane < 16) {
            int pos = p0 + wv * 16 + lane;
            float s = gp * (1.0f / QSCALE_);
            gate[b * N_ + pos] = 1.f / (1.f + __expf(-s));
        }
    }
    __syncthreads();

    int row = tid >> 2;
    int cb  = (tid & 3) << 4;
    ushort4 u[4];
    #pragma unroll
    for (int k = 0; k < 4; ++k)
        u[k] = *reinterpret_cast<ushort4*>(&rp[row * 72 + cb + k * 4]);
    unsigned short* dst;
    if (pass == 0)      dst = Qb + ((size_t)b * N_ + p0 + row) * 64 + cb;
    else if (pass == 1) dst = Kb + ((size_t)b * N_ + p0 + row) * 64 + cb;
    else                dst = Vb + ((size_t)b * 64 + row) * N_ + p0 + cb;
    #pragma unroll
    for (int k = 0; k < 4; ++k)
        *reinterpret_cast<ushort4*>(dst + k * 4) = u[k];
}

// ---------------------------------------------------------------- kernel 2
// Flash attention — round-6 structure (grid 1024, 16 q-rows/wave, 64-q block,
// 4-5 blocks/CU) + S^T orientation: A=K (LDS b128), B=Q (registers).
// C/D puts q on the col axis -> lane's 4 P values consecutive in k:
//   P scatter = 1 ds_write_b64 per kj (was 16 scalar b16 per iter),
//   row-sum in-register via 2 shfl_xor (ones-MFMAs dropped).
// K+V staged with register prefetch across the barrier. bf16 partials.
__global__ __launch_bounds__(256, 4) void attn_kernel(
    const unsigned short* __restrict__ Qb, const unsigned short* __restrict__ Kb,
    const unsigned short* __restrict__ Vb, unsigned short* __restrict__ Opart,
    float* __restrict__ lpart)
{
    __shared__ unsigned short Ks[64 * 72];   // [kpos][d]
    __shared__ unsigned short Vs[64 * 72];   // [c][tj]
    __shared__ unsigned short Ps[64 * 72];   // [qi][k] per-wave 16-row strips

    int tid = threadIdx.x;
    int bx  = blockIdx.x;          // 1024
    int qt  = bx >> 4;             // 0..63
    int grp = bx & 15;             // XCD-pinned (b, ks)
    int b   = grp >> 2;
    int ks  = grp & 3;
    int q0  = qt << 6;
    int kbase = ks << 10;          // 1024-column K window

    int lane = tid & 63;
    int wv   = __builtin_amdgcn_readfirstlane(tid >> 6);
    int quad = lane >> 4, l16 = lane & 15;
    int qs0  = wv << 4;            // wave's 16-row strip base

    // Q B-frags (loop-invariant): B[n=q][k], same layout as A
    const unsigned short* Qg = Qb + ((size_t)b * N_ + q0) * 64;
    bf16x8 bq0 = *reinterpret_cast<const bf16x8*>(&Qg[(qs0 + l16) * 64 + quad * 8]);
    bf16x8 bq1 = *reinterpret_cast<const bf16x8*>(&Qg[(qs0 + l16) * 64 + 32 + quad * 8]);

    const unsigned short* Kg = Kb + ((size_t)b * N_ + kbase) * 64;
    const unsigned short* Vg = Vb + (size_t)b * 64 * N_ + kbase;

    int srow = tid >> 3;           // staging row 0..31 (+32)
    int scol = (tid & 7) << 3;     // ushort offset (16B units)

    uint4 kr[2], vr[2];
    #pragma unroll
    for (int i = 0; i < 2; ++i) {
        int r = srow + 32 * i;
        kr[i] = *reinterpret_cast<const uint4*>(&Kg[(size_t)r * 64 + scol]);
        vr[i] = *reinterpret_cast<const uint4*>(&Vg[(size_t)r * N_ + scol]);
    }

    f32x4 oacc[4]; float lacc = 0.f;
    #pragma unroll
    for (int cs = 0; cs < 4; ++cs) oacc[cs] = (f32x4){0.f, 0.f, 0.f, 0.f};

    for (int kt = 0; kt < 16; ++kt) {
        __syncthreads();                     // prev-iter frag reads done
        #pragma unroll
        for (int i = 0; i < 2; ++i) {
            int r = srow + 32 * i;
            *reinterpret_cast<uint4*>(&Ks[r * 72 + scol]) = kr[i];
            *reinterpret_cast<uint4*>(&Vs[r * 72 + scol]) = vr[i];
        }
        __syncthreads();
        if (kt < 15) {                       // prefetch next tile
            int kk = (kt + 1) << 6;
            #pragma unroll
            for (int i = 0; i < 2; ++i) {
                int r = srow + 32 * i;
                kr[i] = *reinterpret_cast<const uint4*>(&Kg[(size_t)(kk + r) * 64 + scol]);
                vr[i] = *reinterpret_cast<const uint4*>(&Vg[(size_t)r * N_ + kk + scol]);
            }
        }

        // S^T = K.Q^T per kj tile; lane holds S[q=qs0+l16][k=kj*16+quad*4+j]
        float ls = 0.f;
        #pragma unroll
        for (int kj = 0; kj < 4; ++kj) {
            bf16x8 ak0 = *reinterpret_cast<bf16x8*>(&Ks[(kj * 16 + l16) * 72 + quad * 8]);
            bf16x8 ak1 = *reinterpret_cast<bf16x8*>(&Ks[(kj * 16 + l16) * 72 + 32 + quad * 8]);
            f32x4 sv = (f32x4){0.f, 0.f, 0.f, 0.f};
            sv = __builtin_amdgcn_mfma_f32_16x16x32_bf16(ak0, bq0, sv, 0, 0, 0);
            sv = __builtin_amdgcn_mfma_f32_16x16x32_bf16(ak1, bq1, sv, 0, 0, 0);
            float p0v = EXP2(sv[0]), p1v = EXP2(sv[1]);
            float p2v = EXP2(sv[2]), p3v = EXP2(sv[3]);
            ls += (p0v + p1v) + (p2v + p3v);
            uint2 pk;
            pk.x = pack2bf_fast(p0v, p1v);
            pk.y = pack2bf_fast(p2v, p3v);
            *reinterpret_cast<uint2*>(
                &Ps[(qs0 + l16) * 72 + kj * 16 + quad * 4]) = pk;
        }
        // row-sum across quads (lanes with same l16 hold same q)
        ls += __shfl_xor(ls, 16);
        ls += __shfl_xor(ls, 32);
        lacc += ls;
        __asm__ volatile("s_waitcnt lgkmcnt(0)" ::: "memory");  // wave-local strip

        bf16x8 ap0 = *reinterpret_cast<bf16x8*>(&Ps[(qs0 + l16) * 72 + quad * 8]);
        bf16x8 ap1 = *reinterpret_cast<bf16x8*>(&Ps[(qs0 + l16) * 72 + 32 + quad * 8]);
        // O += P.V
        #pragma unroll
        for (int cs = 0; cs < 4; ++cs) {
            bf16x8 bv0 = *reinterpret_cast<bf16x8*>(&Vs[(cs * 16 + l16) * 72 + quad * 8]);
            bf16x8 bv1 = *reinterpret_cast<bf16x8*>(&Vs[(cs * 16 + l16) * 72 + 32 + quad * 8]);
            oacc[cs] = __builtin_amdgcn_mfma_f32_16x16x32_bf16(ap0, bv0, oacc[cs], 0, 0, 0);
            oacc[cs] = __builtin_amdgcn_mfma_f32_16x16x32_bf16(ap1, bv1, oacc[cs], 0, 0, 0);
        }
    }

    // private bf16 partials: each address written exactly once grid-wide
    unsigned short* Og = Opart + (((size_t)ks * B_ + b) * N_ + q0) * 64;
    #pragma unroll
    for (int j = 0; j < 4; ++j) {
        int row = qs0 + quad * 4 + j;
        #pragma unroll
        for (int cs = 0; cs < 4; ++cs)
            Og[row * 64 + cs * 16 + l16] = f2bf_fast(oacc[cs][j]);
    }
    if (quad == 0)
        lpart[((size_t)ks * B_ + b) * N_ + q0 + qs0 + l16] = lacc;
}

// ---------------------------------------------------------------- kernel 3
// MFMA epilogue, grid 256 (b x 64-pos tile), ALL 64 out-channels per block:
// Opart read once (8 MB total), Wo staged once. LDS ~61 KB.
__global__ __launch_bounds__(256) void epi_kernel(
    const unsigned short* __restrict__ Opart, const float* __restrict__ lpart,
    const float* __restrict__ x, const float* __restrict__ gate,
    const float* __restrict__ Wo, const float* __restrict__ bo,
    float* __restrict__ out)
{
    __shared__ float xs[64 * 68];            // [p][c]
    __shared__ float osum[64 * 68];          // [p][c] summed partials
    __shared__ unsigned short Wl[64 * 72];   // [o][c] bf16
    __shared__ float os[64 * 68];            // out repack [o][p]

    int tid  = threadIdx.x;
    int bx   = blockIdx.x;
    int b  = bx >> 6;
    int p0 = (bx & 63) << 6;
    const float* xb = x + (size_t)b * (C_ * N_) + p0;

    // stage x [p][c] via float4 loads
    #pragma unroll
    for (int i = 0; i < 4; ++i) {
        int u = tid + i * 256;
        int c = u >> 4, p4 = (u & 15) << 2;
        float4 v = *reinterpret_cast<const float4*>(&xb[(size_t)c * N_ + p4]);
        xs[(p4 + 0) * 68 + c] = v.x;
        xs[(p4 + 1) * 68 + c] = v.y;
        xs[(p4 + 2) * 68 + c] = v.z;
        xs[(p4 + 3) * 68 + c] = v.w;
    }
    {   // sum 4 bf16 ksplit partials, coalesced uint2 (4 bf16 each)
        const unsigned short* Ob = Opart + ((size_t)b * N_ + p0) * 64;
        const size_t kstride = (size_t)B_ * N_ * 64;   // ushorts
        #pragma unroll
        for (int i = 0; i < 4; ++i) {
            int u = tid + i * 256;           // 1024 units of 4 c
            int p = u >> 4, c4 = (u & 15) << 2;
            size_t off = (size_t)p * 64 + c4;
            uint2 a0 = *reinterpret_cast<const uint2*>(&Ob[off]);
            uint2 a1 = *reinterpret_cast<const uint2*>(&Ob[off + kstride]);
            uint2 a2 = *reinterpret_cast<const uint2*>(&Ob[off + 2 * kstride]);
            uint2 a3 = *reinterpret_cast<const uint2*>(&Ob[off + 3 * kstride]);
            float4 ssum;
            ssum.x = (bflo(a0.x) + bflo(a1.x)) + (bflo(a2.x) + bflo(a3.x));
            ssum.y = (bfhi(a0.x) + bfhi(a1.x)) + (bfhi(a2.x) + bfhi(a3.x));
            ssum.z = (bflo(a0.y) + bflo(a1.y)) + (bflo(a2.y) + bflo(a3.y));
            ssum.w = (bfhi(a0.y) + bfhi(a1.y)) + (bfhi(a2.y) + bfhi(a3.y));
            *reinterpret_cast<float4*>(&osum[p * 68 + c4]) = ssum;
        }
    }
    {   // all 64 Wo rows -> bf16 LDS (16 c per thread)
        int ol = tid >> 2;
        int cb = (tid & 3) << 4;
        const float4* src = reinterpret_cast<const float4*>(&Wo[ol * 64 + cb]);
        float4 w0 = src[0], w1 = src[1], w2 = src[2], w3 = src[3];
        uint4 lo, hi;
        lo.x = pack2bf(w0.x, w0.y); lo.y = pack2bf(w0.z, w0.w);
        lo.z = pack2bf(w1.x, w1.y); lo.w = pack2bf(w1.z, w1.w);
        hi.x = pack2bf(w2.x, w2.y); hi.y = pack2bf(w2.z, w2.w);
        hi.z = pack2bf(w3.x, w3.y); hi.w = pack2bf(w3.z, w3.w);
        *reinterpret_cast<uint4*>(&Wl[ol * 72 + cb])     = lo;
        *reinterpret_cast<uint4*>(&Wl[ol * 72 + cb + 8]) = hi;
    }
    __syncthreads();

    int lane = tid & 63;
    int wv   = __builtin_amdgcn_readfirstlane(tid >> 6);
    int quad = lane >> 4, l16 = lane & 15;
    int prow = wv * 16 + l16;
    int pos  = p0 + prow;

    float lv = lpart[(size_t)b * N_ + pos]
             + lpart[((size_t)B_ + b) * N_ + pos]
             + lpart[(2 * (size_t)B_ + b) * N_ + pos]
             + lpart[(3 * (size_t)B_ + b) * N_ + pos];
    float gi = gate[b * N_ + pos] / lv;

    bf16x8 bt[2];
    #pragma unroll
    for (int chunk = 0; chunk < 2; ++chunk) {
        int cb2 = chunk * 32 + quad * 8;
        float4 oa = *reinterpret_cast<float4*>(&osum[prow * 68 + cb2]);
        float4 ob4 = *reinterpret_cast<float4*>(&osum[prow * 68 + cb2 + 4]);
        float4 xa = *reinterpret_cast<float4*>(&xs[prow * 68 + cb2]);
        float4 xb4 = *reinterpret_cast<float4*>(&xs[prow * 68 + cb2 + 4]);
        bt[chunk][0] = f2bf(fmaf(oa.x, gi, xa.x));
        bt[chunk][1] = f2bf(fmaf(oa.y, gi, xa.y));
        bt[chunk][2] = f2bf(fmaf(oa.z, gi, xa.z));
        bt[chunk][3] = f2bf(fmaf(oa.w, gi, xa.w));
        bt[chunk][4] = f2bf(fmaf(ob4.x, gi, xb4.x));
        bt[chunk][5] = f2bf(fmaf(ob4.y, gi, xb4.y));
        bt[chunk][6] = f2bf(fmaf(ob4.z, gi, xb4.z));
        bt[chunk][7] = f2bf(fmaf(ob4.w, gi, xb4.w));
    }

    #pragma unroll
    for (int tt = 0; tt < 4; ++tt) {
        bf16x8 a0 = *reinterpret_cast<bf16x8*>(&Wl[(tt * 16 + l16) * 72 + quad * 8]);
        bf16x8 a1 = *reinterpret_cast<bf16x8*>(&Wl[(tt * 16 + l16) * 72 + 32 + quad * 8]);
        f32x4 c4 = (f32x4){0.f, 0.f, 0.f, 0.f};
        c4 = __builtin_amdgcn_mfma_f32_16x16x32_bf16(a0, bt[0], c4, 0, 0, 0);
        c4 = __builtin_amdgcn_mfma_f32_16x16x32_bf16(a1, bt[1], c4, 0, 0, 0);
        float4 bias = *reinterpret_cast<const float4*>(&bo[tt * 16 + quad * 4]);
        c4[0] += bias.x; c4[1] += bias.y; c4[2] += bias.z; c4[3] += bias.w;
        #pragma unroll
        for (int j = 0; j < 4; ++j)
            os[(tt * 16 + quad * 4 + j) * 68 + prow] = c4[j];
    }
    __syncthreads();

    // coalesced store: row = out channel, 64 pos each
    int row = tid >> 2;
    int pb  = (tid & 3) << 4;
    float* ob = out + ((size_t)b * 64 + row) * N_ + p0 + pb;
    #pragma unroll
    for (int k = 0; k < 4; ++k)
        *reinterpret_cast<float4*>(ob + k * 4) =
            *reinterpret_cast<float4*>(&os[row * 68 + pb + k * 4]);
}

// ---------------------------------------------------------------- launch
extern "C" void kernel_launch(void* const* d_in, const int* in_sizes, int n_in,
                              void* d_out, int out_size, void* d_ws, size_t ws_size,
                              hipStream_t stream)
{
    const float* x   = (const float*)d_in[0];
    const float* fp  = (const float*)d_in[1];
    const float* Wq  = (const float*)d_in[2];
    const float* bq  = (const float*)d_in[3];
    const float* Wk  = (const float*)d_in[4];
    const float* bk  = (const float*)d_in[5];
    const float* Wv  = (const float*)d_in[6];
    const float* bv  = (const float*)d_in[7];
    const float* Wo  = (const float*)d_in[8];
    const float* bo  = (const float*)d_in[9];
    const float* Wfp = (const float*)d_in[10];
    const float* bfp = (const float*)d_in[11];
    float* out = (float*)d_out;

    char* ws = (char*)d_ws;
    float* gate = (float*)(ws);                                      // 64 KB
    unsigned short* Qb = (unsigned short*)(ws + 65536);              // 2 MB
    unsigned short* Kb = (unsigned short*)(ws + 65536 + 2097152);    // 2 MB
    unsigned short* Vb = (unsigned short*)(ws + 65536 + 2 * 2097152);// 2 MB
    unsigned short* Opart = (unsigned short*)(ws + 65536 + 3 * 2097152); // 8 MB bf16
    float* lpart = (float*)(ws + 65536 + 3 * 2097152 + 8388608);     // 256 KB

    // no memset needed: every Opart/lpart element is written exactly once

    hipLaunchKernelGGL(qkv_kernel, dim3(768), dim3(256), 0, stream,
                       x, Wq, bq, Wk, bk, Wv, bv, fp, Wfp, bfp,
                       gate, Qb, Kb, Vb);
    hipLaunchKernelGGL(attn_kernel, dim3(1024), dim3(256), 0, stream,
                       Qb, Kb, Vb, Opart, lpart);
    hipLaunchKernelGGL(epi_kernel, dim3(256), dim3(256), 0, stream,
                       Opart, lpart, x, gate, Wo, bo, out);
}

// Round 11
// 141.816 us; speedup vs baseline: 1.1350x; 1.1350x over previous
//
#include <hip/hip_runtime.h>
#include <cstdint>
#include <cstddef>

#define B_    4
#define C_    64
#define N_    4096   // 64*64
#define FPD_  128
// fold (1/sqrt(64)) * log2(e) into stored Q so attn does pv = exp2(s)
#define QSCALE_ (0.125f * 1.4426950408889634f)

#if __has_builtin(__builtin_amdgcn_exp2f)
#define EXP2(x) __builtin_amdgcn_exp2f(x)
#else
#define EXP2(x) exp2f(x)
#endif

typedef short bf16x8 __attribute__((ext_vector_type(8)));
typedef float f32x4  __attribute__((ext_vector_type(4)));

__device__ inline unsigned short f2bf(float f) {
    union { float f; unsigned int u; } v; v.f = f;
    unsigned int u = v.u;
    return (unsigned short)((u + 0x7FFFu + ((u >> 16) & 1u)) >> 16);  // RNE
}
__device__ inline unsigned int pack2bf(float a, float b) {
    return (unsigned int)f2bf(a) | ((unsigned int)f2bf(b) << 16);
}
// round-half-up bf16 (2 ops); differs from RNE only on exact ties
__device__ inline unsigned short f2bf_fast(float f) {
    union { float f; unsigned int u; } v; v.f = f;
    return (unsigned short)((v.u + 0x8000u) >> 16);
}
__device__ inline float bflo(unsigned int u) {
    union { unsigned int u; float f; } v; v.u = u << 16; return v.f;
}
__device__ inline float bfhi(unsigned int u) {
    union { unsigned int u; float f; } v; v.u = u & 0xFFFF0000u; return v.f;
}

// ---------------------------------------------------------------- kernel 1
// Fused prep+QKV. Grid 768: pass = bx>>8 (0=Q,1=K,2=V), rem = bx&255 ->
// (b, 64-position tile). Pass 0 also computes fp_proj in-block and the gate.
__global__ __launch_bounds__(256) void qkv_kernel(
    const float* __restrict__ x,
    const float* __restrict__ Wq, const float* __restrict__ bq,
    const float* __restrict__ Wk, const float* __restrict__ bk,
    const float* __restrict__ Wv, const float* __restrict__ bv,
    const float* __restrict__ fp, const float* __restrict__ Wfp,
    const float* __restrict__ bfp,
    float* __restrict__ gate,
    unsigned short* __restrict__ Qb, unsigned short* __restrict__ Kb,
    unsigned short* __restrict__ Vb)
{
    __shared__ unsigned short xT[64 * 72];   // [p][c] bf16
    __shared__ unsigned short Wl[64 * 72];   // [o][c] bf16
    __shared__ unsigned short rp[64 * 72];   // repack
    __shared__ float gredf[256];
    __shared__ float fpp[64];

    int tid  = threadIdx.x;
    int bx   = blockIdx.x;
    int pass = bx >> 8;
    int rem  = bx & 255;
    int b  = rem >> 6;
    int p0 = (rem & 63) << 6;
    const float* xb = x + (size_t)b * (C_ * N_) + p0;

    const float* Wsrc = (pass == 0) ? Wq : (pass == 1) ? Wk : Wv;
    const float* bsrc = (pass == 0) ? bq : (pass == 1) ? bk : bv;
    float wscale = (pass == 0) ? QSCALE_ : 1.0f;

    {   // stage W bf16
        int o  = tid >> 2;
        int cb = (tid & 3) << 4;
        const float4* src = reinterpret_cast<const float4*>(&Wsrc[o * 64 + cb]);
        float4 w0 = src[0], w1 = src[1], w2 = src[2], w3 = src[3];
        uint4 lo, hi;
        lo.x = pack2bf(w0.x * wscale, w0.y * wscale);
        lo.y = pack2bf(w0.z * wscale, w0.w * wscale);
        lo.z = pack2bf(w1.x * wscale, w1.y * wscale);
        lo.w = pack2bf(w1.z * wscale, w1.w * wscale);
        hi.x = pack2bf(w2.x * wscale, w2.y * wscale);
        hi.y = pack2bf(w2.z * wscale, w2.w * wscale);
        hi.z = pack2bf(w3.x * wscale, w3.y * wscale);
        hi.w = pack2bf(w3.z * wscale, w3.w * wscale);
        *reinterpret_cast<uint4*>(&Wl[o * 72 + cb])     = lo;
        *reinterpret_cast<uint4*>(&Wl[o * 72 + cb + 8]) = hi;
    }
    // stage x tile transposed [p][c] bf16 — float4 loads (4 p of one c)
    #pragma unroll
    for (int i = 0; i < 4; ++i) {
        int u = tid + i * 256;               // 1024 units
        int c = u >> 4, p4 = (u & 15) << 2;
        float4 v = *reinterpret_cast<const float4*>(&xb[(size_t)c * N_ + p4]);
        xT[(p4 + 0) * 72 + c] = f2bf(v.x);
        xT[(p4 + 1) * 72 + c] = f2bf(v.y);
        xT[(p4 + 2) * 72 + c] = f2bf(v.z);
        xT[(p4 + 3) * 72 + c] = f2bf(v.w);
    }
    if (pass == 0) {                         // fp_proj
        int d = tid >> 2, kq = tid & 3;
        const float4* wrow = reinterpret_cast<const float4*>(&Wfp[d * FPD_ + kq * 32]);
        const float4* frow = reinterpret_cast<const float4*>(&fp[b * FPD_ + kq * 32]);
        float s = 0.f;
        #pragma unroll
        for (int i = 0; i < 8; ++i) {
            float4 w4 = wrow[i], f4 = frow[i];
            s += w4.x * f4.x + w4.y * f4.y + w4.z * f4.z + w4.w * f4.w;
        }
        gredf[tid] = s;
    }
    __syncthreads();
    if (pass == 0 && tid < 64)
        fpp[tid] = bfp[tid] + gredf[tid * 4] + gredf[tid * 4 + 1]
                 + gredf[tid * 4 + 2] + gredf[tid * 4 + 3];
    if (pass == 0) __syncthreads();

    int lane = tid & 63;
    int wv   = __builtin_amdgcn_readfirstlane(tid >> 6);
    int quad = lane >> 4, l16 = lane & 15;
    int prow = wv * 16 + l16;

    bf16x8 bx0 = *reinterpret_cast<bf16x8*>(&xT[prow * 72 + quad * 8]);
    bf16x8 bx1 = *reinterpret_cast<bf16x8*>(&xT[prow * 72 + 32 + quad * 8]);

    float gp = 0.f;
    #pragma unroll
    for (int t4 = 0; t4 < 4; ++t4) {
        bf16x8 a0 = *reinterpret_cast<bf16x8*>(&Wl[(t4 * 16 + l16) * 72 + quad * 8]);
        bf16x8 a1 = *reinterpret_cast<bf16x8*>(&Wl[(t4 * 16 + l16) * 72 + 32 + quad * 8]);
        f32x4 c4 = (f32x4){0.f, 0.f, 0.f, 0.f};
        c4 = __builtin_amdgcn_mfma_f32_16x16x32_bf16(a0, bx0, c4, 0, 0, 0);
        c4 = __builtin_amdgcn_mfma_f32_16x16x32_bf16(a1, bx1, c4, 0, 0, 0);
        float4 bias = *reinterpret_cast<const float4*>(&bsrc[t4 * 16 + quad * 4]);
        c4[0] += bias.x * wscale; c4[1] += bias.y * wscale;
        c4[2] += bias.z * wscale; c4[3] += bias.w * wscale;
        if (pass == 0) {
            gp = fmaf(c4[0], fpp[t4 * 16 + quad * 4 + 0], gp);
            gp = fmaf(c4[1], fpp[t4 * 16 + quad * 4 + 1], gp);
            gp = fmaf(c4[2], fpp[t4 * 16 + quad * 4 + 2], gp);
            gp = fmaf(c4[3], fpp[t4 * 16 + quad * 4 + 3], gp);
        }
        if (pass < 2) {
            int dd = t4 * 16 + quad * 4;
            *reinterpret_cast<ushort2*>(&rp[prow * 72 + dd]) =
                (ushort2){f2bf(c4[0]), f2bf(c4[1])};
            *reinterpret_cast<ushort2*>(&rp[prow * 72 + dd + 2]) =
                (ushort2){f2bf(c4[2]), f2bf(c4[3])};
        } else {
            #pragma unroll
            for (int j = 0; j < 4; ++j)
                rp[(t4 * 16 + quad * 4 + j) * 72 + prow] = f2bf(c4[j]);
        }
    }
    if (pass == 0) {
        gp += __shfl_xor(gp, 16);
        gp += __shfl_xor(gp, 32);
        if (lane < 16) {
            int pos = p0 + wv * 16 + lane;
            float s = gp * (1.0f / QSCALE_);
            gate[b * N_ + pos] = 1.f / (1.f + __expf(-s));
        }
    }
    __syncthreads();

    int row = tid >> 2;
    int cb  = (tid & 3) << 4;
    ushort4 u[4];
    #pragma unroll
    for (int k = 0; k < 4; ++k)
        u[k] = *reinterpret_cast<ushort4*>(&rp[row * 72 + cb + k * 4]);
    unsigned short* dst;
    if (pass == 0)      dst = Qb + ((size_t)b * N_ + p0 + row) * 64 + cb;
    else if (pass == 1) dst = Kb + ((size_t)b * N_ + p0 + row) * 64 + cb;
    else                dst = Vb + ((size_t)b * 64 + row) * N_ + p0 + cb;
    #pragma unroll
    for (int k = 0; k < 4; ++k)
        *reinterpret_cast<ushort4*>(dst + k * 4) = u[k];
}

// ---------------------------------------------------------------- kernel 2
// Flash attention, 16x16x32 core, 32 q-rows per wave (128 q/block):
// K/V fragment reads shared across both q-strips -> 1.6x less LDS traffic.
// Grid 512 = 4b x 32 qtiles x 4 ksplit. Private bf16 partials, no atomics.
// (Round-7 configuration — best measured: total 118.6 us.)
__global__ __launch_bounds__(256, 2) void attn_kernel(
    const unsigned short* __restrict__ Qb, const unsigned short* __restrict__ Kb,
    const unsigned short* __restrict__ Vb, unsigned short* __restrict__ Opart,
    float* __restrict__ lpart)
{
    __shared__ unsigned short Ks[64 * 72];    // [kj][d]
    __shared__ unsigned short Vs[64 * 72];    // [c][tj]
    __shared__ unsigned short Ps[128 * 72];   // [qi][tj] per-wave 32-row strips

    int tid = threadIdx.x;
    int bx  = blockIdx.x;          // 512
    int qt  = bx >> 4;             // 0..31
    int grp = bx & 15;
    int b   = grp >> 2;
    int ks  = grp & 3;
    int q0  = qt << 7;             // 128-row q tile
    int kbase = ks << 10;          // 1024-column K window

    int lane = tid & 63;
    int wv   = __builtin_amdgcn_readfirstlane(tid >> 6);
    int quad = lane >> 4, l16 = lane & 15;
    int qs0  = wv << 5;            // wave's 32-row strip base

    // Q A-frags for both 16-row strips (loop-invariant)
    const unsigned short* Qg = Qb + ((size_t)b * N_ + q0) * 64;
    bf16x8 aq[2][2];
    #pragma unroll
    for (int s = 0; s < 2; ++s) {
        aq[s][0] = *reinterpret_cast<const bf16x8*>(
            &Qg[(qs0 + s * 16 + l16) * 64 + quad * 8]);
        aq[s][1] = *reinterpret_cast<const bf16x8*>(
            &Qg[(qs0 + s * 16 + l16) * 64 + 32 + quad * 8]);
    }

    const unsigned short* Kg = Kb + ((size_t)b * N_ + kbase) * 64;
    const unsigned short* Vg = Vb + (size_t)b * 64 * N_ + kbase;

    int srow = tid >> 3;           // V staging row 0..31 (+32)
    int scol = (tid & 7) << 3;     // ushort offset (16B units)

    uint4 kr[2], vr[2];
    #pragma unroll
    for (int i = 0; i < 2; ++i) {
        int r = srow + 32 * i;
        kr[i] = *reinterpret_cast<const uint4*>(&Kg[(size_t)r * 64 + scol]);
        vr[i] = *reinterpret_cast<const uint4*>(&Vg[(size_t)r * N_ + scol]);
    }

    f32x4 oacc[2][4]; f32x4 lacc[2];
    #pragma unroll
    for (int s = 0; s < 2; ++s) {
        lacc[s] = (f32x4){0.f, 0.f, 0.f, 0.f};
        #pragma unroll
        for (int cs = 0; cs < 4; ++cs) oacc[s][cs] = (f32x4){0.f, 0.f, 0.f, 0.f};
    }
    bf16x8 ones;
    #pragma unroll
    for (int i = 0; i < 8; ++i) ones[i] = (short)0x3F80;   // bf16 1.0

    for (int kt = 0; kt < 16; ++kt) {
        __syncthreads();                     // prev-iter frag reads done
        #pragma unroll
        for (int i = 0; i < 2; ++i) {
            int r = srow + 32 * i;
            *reinterpret_cast<uint4*>(&Ks[r * 72 + scol]) = kr[i];
            *reinterpret_cast<uint4*>(&Vs[r * 72 + scol]) = vr[i];
        }
        __syncthreads();
        if (kt < 15) {                       // prefetch next tile
            int kk = (kt + 1) << 6;
            #pragma unroll
            for (int i = 0; i < 2; ++i) {
                int r = srow + 32 * i;
                kr[i] = *reinterpret_cast<const uint4*>(&Kg[(size_t)(kk + r) * 64 + scol]);
                vr[i] = *reinterpret_cast<const uint4*>(&Vg[(size_t)r * N_ + kk + scol]);
            }
        }

        // S = Q K^T, P = exp2(S) -> Ps  (K-frags shared across both strips)
        #pragma unroll
        for (int kj = 0; kj < 4; ++kj) {
            bf16x8 bk0 = *reinterpret_cast<bf16x8*>(&Ks[(kj * 16 + l16) * 72 + quad * 8]);
            bf16x8 bk1 = *reinterpret_cast<bf16x8*>(&Ks[(kj * 16 + l16) * 72 + 32 + quad * 8]);
            #pragma unroll
            for (int s = 0; s < 2; ++s) {
                f32x4 sv = (f32x4){0.f, 0.f, 0.f, 0.f};
                sv = __builtin_amdgcn_mfma_f32_16x16x32_bf16(aq[s][0], bk0, sv, 0, 0, 0);
                sv = __builtin_amdgcn_mfma_f32_16x16x32_bf16(aq[s][1], bk1, sv, 0, 0, 0);
                #pragma unroll
                for (int j = 0; j < 4; ++j) {
                    float pv = EXP2(sv[j]);
                    Ps[(qs0 + s * 16 + quad * 4 + j) * 72 + kj * 16 + l16] = f2bf_fast(pv);
                }
            }
        }
        __asm__ volatile("s_waitcnt lgkmcnt(0)" ::: "memory");  // wave-local strip

        bf16x8 ap[2][2];
        #pragma unroll
        for (int s = 0; s < 2; ++s) {
            ap[s][0] = *reinterpret_cast<bf16x8*>(&Ps[(qs0 + s * 16 + l16) * 72 + quad * 8]);
            ap[s][1] = *reinterpret_cast<bf16x8*>(&Ps[(qs0 + s * 16 + l16) * 72 + 32 + quad * 8]);
            lacc[s] = __builtin_amdgcn_mfma_f32_16x16x32_bf16(ap[s][0], ones, lacc[s], 0, 0, 0);
            lacc[s] = __builtin_amdgcn_mfma_f32_16x16x32_bf16(ap[s][1], ones, lacc[s], 0, 0, 0);
        }
        // O += P.V   (V-frags shared across both strips)
        #pragma unroll
        for (int cs = 0; cs < 4; ++cs) {
            bf16x8 bv0 = *reinterpret_cast<bf16x8*>(&Vs[(cs * 16 + l16) * 72 + quad * 8]);
            bf16x8 bv1 = *reinterpret_cast<bf16x8*>(&Vs[(cs * 16 + l16) * 72 + 32 + quad * 8]);
            #pragma unroll
            for (int s = 0; s < 2; ++s) {
                oacc[s][cs] = __builtin_amdgcn_mfma_f32_16x16x32_bf16(ap[s][0], bv0, oacc[s][cs], 0, 0, 0);
                oacc[s][cs] = __builtin_amdgcn_mfma_f32_16x16x32_bf16(ap[s][1], bv1, oacc[s][cs], 0, 0, 0);
            }
        }
    }

    // private bf16 partials: each address written exactly once grid-wide
    unsigned short* Og = Opart + (((size_t)ks * B_ + b) * N_ + q0) * 64;
    #pragma unroll
    for (int s = 0; s < 2; ++s)
        #pragma unroll
        for (int j = 0; j < 4; ++j) {
            int row = qs0 + s * 16 + quad * 4 + j;
            #pragma unroll
            for (int cs = 0; cs < 4; ++cs)
                Og[row * 64 + cs * 16 + l16] = f2bf_fast(oacc[s][cs][j]);
        }
    if (l16 == 0) {
        #pragma unroll
        for (int s = 0; s < 2; ++s)
            #pragma unroll
            for (int j = 0; j < 4; ++j)
                lpart[((size_t)ks * B_ + b) * N_ + q0 + qs0 + s * 16 + quad * 4 + j]
                    = lacc[s][j];
    }
}

// ---------------------------------------------------------------- kernel 3
// MFMA epilogue, channel halves (grid 512): bf16 partials summed coalesced
// into fp32 LDS, float4 x staging, then frags from LDS.
__global__ __launch_bounds__(256) void epi_kernel(
    const unsigned short* __restrict__ Opart, const float* __restrict__ lpart,
    const float* __restrict__ x, const float* __restrict__ gate,
    const float* __restrict__ Wo, const float* __restrict__ bo,
    float* __restrict__ out)
{
    __shared__ float xs[64 * 68];            // [p][c]
    __shared__ float osum[64 * 68];          // [p][c] summed partials
    __shared__ unsigned short Wl[32 * 72];   // [o_local][c] bf16
    __shared__ float os[32 * 68];            // out repack [o_local][p]

    int tid  = threadIdx.x;
    int bx   = blockIdx.x;
    int half = bx >> 8;
    int rem  = bx & 255;
    int b  = rem >> 6;
    int p0 = (rem & 63) << 6;
    const float* xb = x + (size_t)b * (C_ * N_) + p0;

    // stage x [p][c] via float4 loads
    #pragma unroll
    for (int i = 0; i < 4; ++i) {
        int u = tid + i * 256;
        int c = u >> 4, p4 = (u & 15) << 2;
        float4 v = *reinterpret_cast<const float4*>(&xb[(size_t)c * N_ + p4]);
        xs[(p4 + 0) * 68 + c] = v.x;
        xs[(p4 + 1) * 68 + c] = v.y;
        xs[(p4 + 2) * 68 + c] = v.z;
        xs[(p4 + 3) * 68 + c] = v.w;
    }
    {   // sum 4 bf16 ksplit partials, coalesced uint2 (4 bf16 each)
        const unsigned short* Ob = Opart + ((size_t)b * N_ + p0) * 64;
        const size_t kstride = (size_t)B_ * N_ * 64;   // ushorts
        #pragma unroll
        for (int i = 0; i < 4; ++i) {
            int u = tid + i * 256;           // 1024 units of 4 c
            int p = u >> 4, c4 = (u & 15) << 2;
            size_t off = (size_t)p * 64 + c4;
            uint2 a0 = *reinterpret_cast<const uint2*>(&Ob[off]);
            uint2 a1 = *reinterpret_cast<const uint2*>(&Ob[off + kstride]);
            uint2 a2 = *reinterpret_cast<const uint2*>(&Ob[off + 2 * kstride]);
            uint2 a3 = *reinterpret_cast<const uint2*>(&Ob[off + 3 * kstride]);
            float4 ssum;
            ssum.x = (bflo(a0.x) + bflo(a1.x)) + (bflo(a2.x) + bflo(a3.x));
            ssum.y = (bfhi(a0.x) + bfhi(a1.x)) + (bfhi(a2.x) + bfhi(a3.x));
            ssum.z = (bflo(a0.y) + bflo(a1.y)) + (bflo(a2.y) + bflo(a3.y));
            ssum.w = (bfhi(a0.y) + bfhi(a1.y)) + (bfhi(a2.y) + bfhi(a3.y));
            *reinterpret_cast<float4*>(&osum[p * 68 + c4]) = ssum;
        }
    }
    {   // Wo rows half*32..+31 -> bf16 LDS
        int ol = tid >> 3;
        int cb = (tid & 7) << 3;
        const float4* src = reinterpret_cast<const float4*>(
            &Wo[(half * 32 + ol) * 64 + cb]);
        float4 w0 = src[0], w1 = src[1];
        uint2 pkd;
        pkd.x = pack2bf(w0.x, w0.y); pkd.y = pack2bf(w0.z, w0.w);
        *reinterpret_cast<uint2*>(&Wl[ol * 72 + cb]) = pkd;
        pkd.x = pack2bf(w1.x, w1.y); pkd.y = pack2bf(w1.z, w1.w);
        *reinterpret_cast<uint2*>(&Wl[ol * 72 + cb + 4]) = pkd;
    }
    __syncthreads();

    int lane = tid & 63;
    int wv   = __builtin_amdgcn_readfirstlane(tid >> 6);
    int quad = lane >> 4, l16 = lane & 15;
    int prow = wv * 16 + l16;
    int pos  = p0 + prow;

    float lv = lpart[(size_t)b * N_ + pos]
             + lpart[((size_t)B_ + b) * N_ + pos]
             + lpart[(2 * (size_t)B_ + b) * N_ + pos]
             + lpart[(3 * (size_t)B_ + b) * N_ + pos];
    float gi = gate[b * N_ + pos] / lv;

    bf16x8 bt[2];
    #pragma unroll
    for (int chunk = 0; chunk < 2; ++chunk) {
        int cb2 = chunk * 32 + quad * 8;
        float4 oa = *reinterpret_cast<float4*>(&osum[prow * 68 + cb2]);
        float4 ob4 = *reinterpret_cast<float4*>(&osum[prow * 68 + cb2 + 4]);
        float4 xa = *reinterpret_cast<float4*>(&xs[prow * 68 + cb2]);
        float4 xb4 = *reinterpret_cast<float4*>(&xs[prow * 68 + cb2 + 4]);
        bt[chunk][0] = f2bf(fmaf(oa.x, gi, xa.x));
        bt[chunk][1] = f2bf(fmaf(oa.y, gi, xa.y));
        bt[chunk][2] = f2bf(fmaf(oa.z, gi, xa.z));
        bt[chunk][3] = f2bf(fmaf(oa.w, gi, xa.w));
        bt[chunk][4] = f2bf(fmaf(ob4.x, gi, xb4.x));
        bt[chunk][5] = f2bf(fmaf(ob4.y, gi, xb4.y));
        bt[chunk][6] = f2bf(fmaf(ob4.z, gi, xb4.z));
        bt[chunk][7] = f2bf(fmaf(ob4.w, gi, xb4.w));
    }

    #pragma unroll
    for (int tt = 0; tt < 2; ++tt) {
        int ot = half * 2 + tt;
        bf16x8 a0 = *reinterpret_cast<bf16x8*>(&Wl[(tt * 16 + l16) * 72 + quad * 8]);
        bf16x8 a1 = *reinterpret_cast<bf16x8*>(&Wl[(tt * 16 + l16) * 72 + 32 + quad * 8]);
        f32x4 c4 = (f32x4){0.f, 0.f, 0.f, 0.f};
        c4 = __builtin_amdgcn_mfma_f32_16x16x32_bf16(a0, bt[0], c4, 0, 0, 0);
        c4 = __builtin_amdgcn_mfma_f32_16x16x32_bf16(a1, bt[1], c4, 0, 0, 0);
        float4 bias = *reinterpret_cast<const float4*>(&bo[ot * 16 + quad * 4]);
        c4[0] += bias.x; c4[1] += bias.y; c4[2] += bias.z; c4[3] += bias.w;
        #pragma unroll
        for (int j = 0; j < 4; ++j)
            os[(tt * 16 + quad * 4 + j) * 68 + prow] = c4[j];
    }
    __syncthreads();

    int row = tid >> 3;
    int pb  = (tid & 7) << 3;
    float* ob = out + ((size_t)b * 64 + half * 32 + row) * N_ + p0 + pb;
    *reinterpret_cast<float4*>(ob)     = *reinterpret_cast<float4*>(&os[row * 68 + pb]);
    *reinterpret_cast<float4*>(ob + 4) = *reinterpret_cast<float4*>(&os[row * 68 + pb + 4]);
}

// ---------------------------------------------------------------- launch
extern "C" void kernel_launch(void* const* d_in, const int* in_sizes, int n_in,
                              void* d_out, int out_size, void* d_ws, size_t ws_size,
                              hipStream_t stream)
{
    const float* x   = (const float*)d_in[0];
    const float* fp  = (const float*)d_in[1];
    const float* Wq  = (const float*)d_in[2];
    const float* bq  = (const float*)d_in[3];
    const float* Wk  = (const float*)d_in[4];
    const float* bk  = (const float*)d_in[5];
    const float* Wv  = (const float*)d_in[6];
    const float* bv  = (const float*)d_in[7];
    const float* Wo  = (const float*)d_in[8];
    const float* bo  = (const float*)d_in[9];
    const float* Wfp = (const float*)d_in[10];
    const float* bfp = (const float*)d_in[11];
    float* out = (float*)d_out;

    char* ws = (char*)d_ws;
    float* gate = (float*)(ws);                                      // 64 KB
    unsigned short* Qb = (unsigned short*)(ws + 65536);              // 2 MB
    unsigned short* Kb = (unsigned short*)(ws + 65536 + 2097152);    // 2 MB
    unsigned short* Vb = (unsigned short*)(ws + 65536 + 2 * 2097152);// 2 MB
    unsigned short* Opart = (unsigned short*)(ws + 65536 + 3 * 2097152); // 8 MB bf16
    float* lpart = (float*)(ws + 65536 + 3 * 2097152 + 8388608);     // 256 KB

    // no memset needed: every Opart/lpart element is written exactly once

    hipLaunchKernelGGL(qkv_kernel, dim3(768), dim3(256), 0, stream,
                       x, Wq, bq, Wk, bk, Wv, bv, fp, Wfp, bfp,
                       gate, Qb, Kb, Vb);
    hipLaunchKernelGGL(attn_kernel, dim3(512), dim3(256), 0, stream,
                       Qb, Kb, Vb, Opart, lpart);
    hipLaunchKernelGGL(epi_kernel, dim3(512), dim3(256), 0, stream,
                       Opart, lpart, x, gate, Wo, bo, out);
}

// Round 12
// 133.581 us; speedup vs baseline: 1.2050x; 1.0617x over previous
//
#include <hip/hip_runtime.h>
#include <cstdint>
#include <cstddef>

#define B_    4
#define C_    64
#define N_    4096   // 64*64
#define FPD_  128
#define KSPLIT_ 8
// fold (1/sqrt(64)) * log2(e) into stored Q so attn does pv = exp2(s)
#define QSCALE_ (0.125f * 1.4426950408889634f)

#if __has_builtin(__builtin_amdgcn_exp2f)
#define EXP2(x) __builtin_amdgcn_exp2f(x)
#else
#define EXP2(x) exp2f(x)
#endif

typedef short bf16x8 __attribute__((ext_vector_type(8)));
typedef float f32x4  __attribute__((ext_vector_type(4)));

__device__ inline unsigned short f2bf(float f) {
    union { float f; unsigned int u; } v; v.f = f;
    unsigned int u = v.u;
    return (unsigned short)((u + 0x7FFFu + ((u >> 16) & 1u)) >> 16);  // RNE
}
__device__ inline unsigned int pack2bf(float a, float b) {
    return (unsigned int)f2bf(a) | ((unsigned int)f2bf(b) << 16);
}
// round-half-up bf16 (2 ops); differs from RNE only on exact ties
__device__ inline unsigned short f2bf_fast(float f) {
    union { float f; unsigned int u; } v; v.f = f;
    return (unsigned short)((v.u + 0x8000u) >> 16);
}
__device__ inline float bflo(unsigned int u) {
    union { unsigned int u; float f; } v; v.u = u << 16; return v.f;
}
__device__ inline float bfhi(unsigned int u) {
    union { unsigned int u; float f; } v; v.u = u & 0xFFFF0000u; return v.f;
}

// ---------------------------------------------------------------- kernel 1
// Fused prep+QKV. Grid 768: pass = bx>>8 (0=Q,1=K,2=V), rem = bx&255 ->
// (b, 64-position tile). Pass 0 also computes fp_proj in-block and the gate.
__global__ __launch_bounds__(256) void qkv_kernel(
    const float* __restrict__ x,
    const float* __restrict__ Wq, const float* __restrict__ bq,
    const float* __restrict__ Wk, const float* __restrict__ bk,
    const float* __restrict__ Wv, const float* __restrict__ bv,
    const float* __restrict__ fp, const float* __restrict__ Wfp,
    const float* __restrict__ bfp,
    float* __restrict__ gate,
    unsigned short* __restrict__ Qb, unsigned short* __restrict__ Kb,
    unsigned short* __restrict__ Vb)
{
    __shared__ unsigned short xT[64 * 72];   // [p][c] bf16
    __shared__ unsigned short Wl[64 * 72];   // [o][c] bf16
    __shared__ unsigned short rp[64 * 72];   // repack
    __shared__ float gredf[256];
    __shared__ float fpp[64];

    int tid  = threadIdx.x;
    int bx   = blockIdx.x;
    int pass = bx >> 8;
    int rem  = bx & 255;
    int b  = rem >> 6;
    int p0 = (rem & 63) << 6;
    const float* xb = x + (size_t)b * (C_ * N_) + p0;

    const float* Wsrc = (pass == 0) ? Wq : (pass == 1) ? Wk : Wv;
    const float* bsrc = (pass == 0) ? bq : (pass == 1) ? bk : bv;
    float wscale = (pass == 0) ? QSCALE_ : 1.0f;

    {   // stage W bf16
        int o  = tid >> 2;
        int cb = (tid & 3) << 4;
        const float4* src = reinterpret_cast<const float4*>(&Wsrc[o * 64 + cb]);
        float4 w0 = src[0], w1 = src[1], w2 = src[2], w3 = src[3];
        uint4 lo, hi;
        lo.x = pack2bf(w0.x * wscale, w0.y * wscale);
        lo.y = pack2bf(w0.z * wscale, w0.w * wscale);
        lo.z = pack2bf(w1.x * wscale, w1.y * wscale);
        lo.w = pack2bf(w1.z * wscale, w1.w * wscale);
        hi.x = pack2bf(w2.x * wscale, w2.y * wscale);
        hi.y = pack2bf(w2.z * wscale, w2.w * wscale);
        hi.z = pack2bf(w3.x * wscale, w3.y * wscale);
        hi.w = pack2bf(w3.z * wscale, w3.w * wscale);
        *reinterpret_cast<uint4*>(&Wl[o * 72 + cb])     = lo;
        *reinterpret_cast<uint4*>(&Wl[o * 72 + cb + 8]) = hi;
    }
    // stage x tile transposed [p][c] bf16 — float4 loads (4 p of one c)
    #pragma unroll
    for (int i = 0; i < 4; ++i) {
        int u = tid + i * 256;               // 1024 units
        int c = u >> 4, p4 = (u & 15) << 2;
        float4 v = *reinterpret_cast<const float4*>(&xb[(size_t)c * N_ + p4]);
        xT[(p4 + 0) * 72 + c] = f2bf(v.x);
        xT[(p4 + 1) * 72 + c] = f2bf(v.y);
        xT[(p4 + 2) * 72 + c] = f2bf(v.z);
        xT[(p4 + 3) * 72 + c] = f2bf(v.w);
    }
    if (pass == 0) {                         // fp_proj
        int d = tid >> 2, kq = tid & 3;
        const float4* wrow = reinterpret_cast<const float4*>(&Wfp[d * FPD_ + kq * 32]);
        const float4* frow = reinterpret_cast<const float4*>(&fp[b * FPD_ + kq * 32]);
        float s = 0.f;
        #pragma unroll
        for (int i = 0; i < 8; ++i) {
            float4 w4 = wrow[i], f4 = frow[i];
            s += w4.x * f4.x + w4.y * f4.y + w4.z * f4.z + w4.w * f4.w;
        }
        gredf[tid] = s;
    }
    __syncthreads();
    if (pass == 0 && tid < 64)
        fpp[tid] = bfp[tid] + gredf[tid * 4] + gredf[tid * 4 + 1]
                 + gredf[tid * 4 + 2] + gredf[tid * 4 + 3];
    if (pass == 0) __syncthreads();

    int lane = tid & 63;
    int wv   = __builtin_amdgcn_readfirstlane(tid >> 6);
    int quad = lane >> 4, l16 = lane & 15;
    int prow = wv * 16 + l16;

    bf16x8 bx0 = *reinterpret_cast<bf16x8*>(&xT[prow * 72 + quad * 8]);
    bf16x8 bx1 = *reinterpret_cast<bf16x8*>(&xT[prow * 72 + 32 + quad * 8]);

    float gp = 0.f;
    #pragma unroll
    for (int t4 = 0; t4 < 4; ++t4) {
        bf16x8 a0 = *reinterpret_cast<bf16x8*>(&Wl[(t4 * 16 + l16) * 72 + quad * 8]);
        bf16x8 a1 = *reinterpret_cast<bf16x8*>(&Wl[(t4 * 16 + l16) * 72 + 32 + quad * 8]);
        f32x4 c4 = (f32x4){0.f, 0.f, 0.f, 0.f};
        c4 = __builtin_amdgcn_mfma_f32_16x16x32_bf16(a0, bx0, c4, 0, 0, 0);
        c4 = __builtin_amdgcn_mfma_f32_16x16x32_bf16(a1, bx1, c4, 0, 0, 0);
        float4 bias = *reinterpret_cast<const float4*>(&bsrc[t4 * 16 + quad * 4]);
        c4[0] += bias.x * wscale; c4[1] += bias.y * wscale;
        c4[2] += bias.z * wscale; c4[3] += bias.w * wscale;
        if (pass == 0) {
            gp = fmaf(c4[0], fpp[t4 * 16 + quad * 4 + 0], gp);
            gp = fmaf(c4[1], fpp[t4 * 16 + quad * 4 + 1], gp);
            gp = fmaf(c4[2], fpp[t4 * 16 + quad * 4 + 2], gp);
            gp = fmaf(c4[3], fpp[t4 * 16 + quad * 4 + 3], gp);
        }
        if (pass < 2) {
            int dd = t4 * 16 + quad * 4;
            *reinterpret_cast<ushort2*>(&rp[prow * 72 + dd]) =
                (ushort2){f2bf(c4[0]), f2bf(c4[1])};
            *reinterpret_cast<ushort2*>(&rp[prow * 72 + dd + 2]) =
                (ushort2){f2bf(c4[2]), f2bf(c4[3])};
        } else {
            #pragma unroll
            for (int j = 0; j < 4; ++j)
                rp[(t4 * 16 + quad * 4 + j) * 72 + prow] = f2bf(c4[j]);
        }
    }
    if (pass == 0) {
        gp += __shfl_xor(gp, 16);
        gp += __shfl_xor(gp, 32);
        if (lane < 16) {
            int pos = p0 + wv * 16 + lane;
            float s = gp * (1.0f / QSCALE_);
            gate[b * N_ + pos] = 1.f / (1.f + __expf(-s));
        }
    }
    __syncthreads();

    int row = tid >> 2;
    int cb  = (tid & 3) << 4;
    ushort4 u[4];
    #pragma unroll
    for (int k = 0; k < 4; ++k)
        u[k] = *reinterpret_cast<ushort4*>(&rp[row * 72 + cb + k * 4]);
    unsigned short* dst;
    if (pass == 0)      dst = Qb + ((size_t)b * N_ + p0 + row) * 64 + cb;
    else if (pass == 1) dst = Kb + ((size_t)b * N_ + p0 + row) * 64 + cb;
    else                dst = Vb + ((size_t)b * 64 + row) * N_ + p0 + cb;
    #pragma unroll
    for (int k = 0; k < 4; ++k)
        *reinterpret_cast<ushort4*>(dst + k * 4) = u[k];
}

// ---------------------------------------------------------------- kernel 2
// Flash attention, 16x16x32 core, 32 q-rows per wave (128 q/block):
// K/V fragment reads shared across both q-strips. KSPLIT x8 -> grid 1024
// = 4 blocks/CU (LDS 36.9 KB x4 = 147/160 KB) for latency hiding; the
// no-max softmax is purely additive so ksplit is free. Private bf16
// partials, no atomics.
__global__ __launch_bounds__(256, 4) void attn_kernel(
    const unsigned short* __restrict__ Qb, const unsigned short* __restrict__ Kb,
    const unsigned short* __restrict__ Vb, unsigned short* __restrict__ Opart,
    float* __restrict__ lpart)
{
    __shared__ unsigned short Ks[64 * 72];    // [kj][d]
    __shared__ unsigned short Vs[64 * 72];    // [c][tj]
    __shared__ unsigned short Ps[128 * 72];   // [qi][tj] per-wave 32-row strips

    int tid = threadIdx.x;
    int bx  = blockIdx.x;          // 1024
    int qt  = bx >> 5;             // 0..31
    int grp = bx & 31;             // XCD-cycled (b, ks)
    int b   = grp >> 3;
    int ks  = grp & 7;
    int q0  = qt << 7;             // 128-row q tile
    int kbase = ks << 9;           // 512-column K window

    int lane = tid & 63;
    int wv   = __builtin_amdgcn_readfirstlane(tid >> 6);
    int quad = lane >> 4, l16 = lane & 15;
    int qs0  = wv << 5;            // wave's 32-row strip base

    // Q A-frags for both 16-row strips (loop-invariant)
    const unsigned short* Qg = Qb + ((size_t)b * N_ + q0) * 64;
    bf16x8 aq[2][2];
    #pragma unroll
    for (int s = 0; s < 2; ++s) {
        aq[s][0] = *reinterpret_cast<const bf16x8*>(
            &Qg[(qs0 + s * 16 + l16) * 64 + quad * 8]);
        aq[s][1] = *reinterpret_cast<const bf16x8*>(
            &Qg[(qs0 + s * 16 + l16) * 64 + 32 + quad * 8]);
    }

    const unsigned short* Kg = Kb + ((size_t)b * N_ + kbase) * 64;
    const unsigned short* Vg = Vb + (size_t)b * 64 * N_ + kbase;

    int srow = tid >> 3;           // staging row 0..31 (+32)
    int scol = (tid & 7) << 3;     // ushort offset (16B units)

    uint4 kr[2], vr[2];
    #pragma unroll
    for (int i = 0; i < 2; ++i) {
        int r = srow + 32 * i;
        kr[i] = *reinterpret_cast<const uint4*>(&Kg[(size_t)r * 64 + scol]);
        vr[i] = *reinterpret_cast<const uint4*>(&Vg[(size_t)r * N_ + scol]);
    }

    f32x4 oacc[2][4]; f32x4 lacc[2];
    #pragma unroll
    for (int s = 0; s < 2; ++s) {
        lacc[s] = (f32x4){0.f, 0.f, 0.f, 0.f};
        #pragma unroll
        for (int cs = 0; cs < 4; ++cs) oacc[s][cs] = (f32x4){0.f, 0.f, 0.f, 0.f};
    }
    bf16x8 ones;
    #pragma unroll
    for (int i = 0; i < 8; ++i) ones[i] = (short)0x3F80;   // bf16 1.0

    for (int kt = 0; kt < 8; ++kt) {         // 512-column window / 64
        __syncthreads();                     // prev-iter frag reads done
        #pragma unroll
        for (int i = 0; i < 2; ++i) {
            int r = srow + 32 * i;
            *reinterpret_cast<uint4*>(&Ks[r * 72 + scol]) = kr[i];
            *reinterpret_cast<uint4*>(&Vs[r * 72 + scol]) = vr[i];
        }
        __syncthreads();
        if (kt < 7) {                        // prefetch next tile
            int kk = (kt + 1) << 6;
            #pragma unroll
            for (int i = 0; i < 2; ++i) {
                int r = srow + 32 * i;
                kr[i] = *reinterpret_cast<const uint4*>(&Kg[(size_t)(kk + r) * 64 + scol]);
                vr[i] = *reinterpret_cast<const uint4*>(&Vg[(size_t)r * N_ + kk + scol]);
            }
        }

        // S = Q K^T, P = exp2(S) -> Ps  (K-frags shared across both strips)
        #pragma unroll
        for (int kj = 0; kj < 4; ++kj) {
            bf16x8 bk0 = *reinterpret_cast<bf16x8*>(&Ks[(kj * 16 + l16) * 72 + quad * 8]);
            bf16x8 bk1 = *reinterpret_cast<bf16x8*>(&Ks[(kj * 16 + l16) * 72 + 32 + quad * 8]);
            #pragma unroll
            for (int s = 0; s < 2; ++s) {
                f32x4 sv = (f32x4){0.f, 0.f, 0.f, 0.f};
                sv = __builtin_amdgcn_mfma_f32_16x16x32_bf16(aq[s][0], bk0, sv, 0, 0, 0);
                sv = __builtin_amdgcn_mfma_f32_16x16x32_bf16(aq[s][1], bk1, sv, 0, 0, 0);
                #pragma unroll
                for (int j = 0; j < 4; ++j) {
                    float pv = EXP2(sv[j]);
                    Ps[(qs0 + s * 16 + quad * 4 + j) * 72 + kj * 16 + l16] = f2bf_fast(pv);
                }
            }
        }
        __asm__ volatile("s_waitcnt lgkmcnt(0)" ::: "memory");  // wave-local strip

        bf16x8 ap[2][2];
        #pragma unroll
        for (int s = 0; s < 2; ++s) {
            ap[s][0] = *reinterpret_cast<bf16x8*>(&Ps[(qs0 + s * 16 + l16) * 72 + quad * 8]);
            ap[s][1] = *reinterpret_cast<bf16x8*>(&Ps[(qs0 + s * 16 + l16) * 72 + 32 + quad * 8]);
            lacc[s] = __builtin_amdgcn_mfma_f32_16x16x32_bf16(ap[s][0], ones, lacc[s], 0, 0, 0);
            lacc[s] = __builtin_amdgcn_mfma_f32_16x16x32_bf16(ap[s][1], ones, lacc[s], 0, 0, 0);
        }
        // O += P.V   (V-frags shared across both strips)
        #pragma unroll
        for (int cs = 0; cs < 4; ++cs) {
            bf16x8 bv0 = *reinterpret_cast<bf16x8*>(&Vs[(cs * 16 + l16) * 72 + quad * 8]);
            bf16x8 bv1 = *reinterpret_cast<bf16x8*>(&Vs[(cs * 16 + l16) * 72 + 32 + quad * 8]);
            #pragma unroll
            for (int s = 0; s < 2; ++s) {
                oacc[s][cs] = __builtin_amdgcn_mfma_f32_16x16x32_bf16(ap[s][0], bv0, oacc[s][cs], 0, 0, 0);
                oacc[s][cs] = __builtin_amdgcn_mfma_f32_16x16x32_bf16(ap[s][1], bv1, oacc[s][cs], 0, 0, 0);
            }
        }
    }

    // private bf16 partials: each address written exactly once grid-wide
    unsigned short* Og = Opart + (((size_t)ks * B_ + b) * N_ + q0) * 64;
    #pragma unroll
    for (int s = 0; s < 2; ++s)
        #pragma unroll
        for (int j = 0; j < 4; ++j) {
            int row = qs0 + s * 16 + quad * 4 + j;
            #pragma unroll
            for (int cs = 0; cs < 4; ++cs)
                Og[row * 64 + cs * 16 + l16] = f2bf_fast(oacc[s][cs][j]);
        }
    if (l16 == 0) {
        #pragma unroll
        for (int s = 0; s < 2; ++s)
            #pragma unroll
            for (int j = 0; j < 4; ++j)
                lpart[((size_t)ks * B_ + b) * N_ + q0 + qs0 + s * 16 + quad * 4 + j]
                    = lacc[s][j];
    }
}

// ---------------------------------------------------------------- kernel 3
// MFMA epilogue, channel halves (grid 512): 8 bf16 ksplit partials summed
// coalesced into fp32 LDS, float4 x staging, then frags from LDS.
__global__ __launch_bounds__(256) void epi_kernel(
    const unsigned short* __restrict__ Opart, const float* __restrict__ lpart,
    const float* __restrict__ x, const float* __restrict__ gate,
    const float* __restrict__ Wo, const float* __restrict__ bo,
    float* __restrict__ out)
{
    __shared__ float xs[64 * 68];            // [p][c]
    __shared__ float osum[64 * 68];          // [p][c] summed partials
    __shared__ unsigned short Wl[32 * 72];   // [o_local][c] bf16
    __shared__ float os[32 * 68];            // out repack [o_local][p]

    int tid  = threadIdx.x;
    int bx   = blockIdx.x;
    int half = bx >> 8;
    int rem  = bx & 255;
    int b  = rem >> 6;
    int p0 = (rem & 63) << 6;
    const float* xb = x + (size_t)b * (C_ * N_) + p0;

    // stage x [p][c] via float4 loads
    #pragma unroll
    for (int i = 0; i < 4; ++i) {
        int u = tid + i * 256;
        int c = u >> 4, p4 = (u & 15) << 2;
        float4 v = *reinterpret_cast<const float4*>(&xb[(size_t)c * N_ + p4]);
        xs[(p4 + 0) * 68 + c] = v.x;
        xs[(p4 + 1) * 68 + c] = v.y;
        xs[(p4 + 2) * 68 + c] = v.z;
        xs[(p4 + 3) * 68 + c] = v.w;
    }
    {   // sum 8 bf16 ksplit partials, coalesced uint2 (4 bf16 each)
        const unsigned short* Ob = Opart + ((size_t)b * N_ + p0) * 64;
        const size_t kstride = (size_t)B_ * N_ * 64;   // ushorts
        #pragma unroll
        for (int i = 0; i < 4; ++i) {
            int u = tid + i * 256;           // 1024 units of 4 c
            int p = u >> 4, c4 = (u & 15) << 2;
            size_t off = (size_t)p * 64 + c4;
            float sx = 0.f, sy = 0.f, sz = 0.f, sw = 0.f;
            #pragma unroll
            for (int kp = 0; kp < KSPLIT_; ++kp) {
                uint2 a = *reinterpret_cast<const uint2*>(&Ob[off + kp * kstride]);
                sx += bflo(a.x); sy += bfhi(a.x);
                sz += bflo(a.y); sw += bfhi(a.y);
            }
            *reinterpret_cast<float4*>(&osum[p * 68 + c4]) =
                (float4){sx, sy, sz, sw};
        }
    }
    {   // Wo rows half*32..+31 -> bf16 LDS
        int ol = tid >> 3;
        int cb = (tid & 7) << 3;
        const float4* src = reinterpret_cast<const float4*>(
            &Wo[(half * 32 + ol) * 64 + cb]);
        float4 w0 = src[0], w1 = src[1];
        uint2 pkd;
        pkd.x = pack2bf(w0.x, w0.y); pkd.y = pack2bf(w0.z, w0.w);
        *reinterpret_cast<uint2*>(&Wl[ol * 72 + cb]) = pkd;
        pkd.x = pack2bf(w1.x, w1.y); pkd.y = pack2bf(w1.z, w1.w);
        *reinterpret_cast<uint2*>(&Wl[ol * 72 + cb + 4]) = pkd;
    }
    __syncthreads();

    int lane = tid & 63;
    int wv   = __builtin_amdgcn_readfirstlane(tid >> 6);
    int quad = lane >> 4, l16 = lane & 15;
    int prow = wv * 16 + l16;
    int pos  = p0 + prow;

    float lv = 0.f;
    #pragma unroll
    for (int kp = 0; kp < KSPLIT_; ++kp)
        lv += lpart[((size_t)kp * B_ + b) * N_ + pos];
    float gi = gate[b * N_ + pos] / lv;

    bf16x8 bt[2];
    #pragma unroll
    for (int chunk = 0; chunk < 2; ++chunk) {
        int cb2 = chunk * 32 + quad * 8;
        float4 oa = *reinterpret_cast<float4*>(&osum[prow * 68 + cb2]);
        float4 ob4 = *reinterpret_cast<float4*>(&osum[prow * 68 + cb2 + 4]);
        float4 xa = *reinterpret_cast<float4*>(&xs[prow * 68 + cb2]);
        float4 xb4 = *reinterpret_cast<float4*>(&xs[prow * 68 + cb2 + 4]);
        bt[chunk][0] = f2bf(fmaf(oa.x, gi, xa.x));
        bt[chunk][1] = f2bf(fmaf(oa.y, gi, xa.y));
        bt[chunk][2] = f2bf(fmaf(oa.z, gi, xa.z));
        bt[chunk][3] = f2bf(fmaf(oa.w, gi, xa.w));
        bt[chunk][4] = f2bf(fmaf(ob4.x, gi, xb4.x));
        bt[chunk][5] = f2bf(fmaf(ob4.y, gi, xb4.y));
        bt[chunk][6] = f2bf(fmaf(ob4.z, gi, xb4.z));
        bt[chunk][7] = f2bf(fmaf(ob4.w, gi, xb4.w));
    }

    #pragma unroll
    for (int tt = 0; tt < 2; ++tt) {
        int ot = half * 2 + tt;
        bf16x8 a0 = *reinterpret_cast<bf16x8*>(&Wl[(tt * 16 + l16) * 72 + quad * 8]);
        bf16x8 a1 = *reinterpret_cast<bf16x8*>(&Wl[(tt * 16 + l16) * 72 + 32 + quad * 8]);
        f32x4 c4 = (f32x4){0.f, 0.f, 0.f, 0.f};
        c4 = __builtin_amdgcn_mfma_f32_16x16x32_bf16(a0, bt[0], c4, 0, 0, 0);
        c4 = __builtin_amdgcn_mfma_f32_16x16x32_bf16(a1, bt[1], c4, 0, 0, 0);
        float4 bias = *reinterpret_cast<const float4*>(&bo[ot * 16 + quad * 4]);
        c4[0] += bias.x; c4[1] += bias.y; c4[2] += bias.z; c4[3] += bias.w;
        #pragma unroll
        for (int j = 0; j < 4; ++j)
            os[(tt * 16 + quad * 4 + j) * 68 + prow] = c4[j];
    }
    __syncthreads();

    int row = tid >> 3;
    int pb  = (tid & 7) << 3;
    float* ob = out + ((size_t)b * 64 + half * 32 + row) * N_ + p0 + pb;
    *reinterpret_cast<float4*>(ob)     = *reinterpret_cast<float4*>(&os[row * 68 + pb]);
    *reinterpret_cast<float4*>(ob + 4) = *reinterpret_cast<float4*>(&os[row * 68 + pb + 4]);
}

// ---------------------------------------------------------------- launch
extern "C" void kernel_launch(void* const* d_in, const int* in_sizes, int n_in,
                              void* d_out, int out_size, void* d_ws, size_t ws_size,
                              hipStream_t stream)
{
    const float* x   = (const float*)d_in[0];
    const float* fp  = (const float*)d_in[1];
    const float* Wq  = (const float*)d_in[2];
    const float* bq  = (const float*)d_in[3];
    const float* Wk  = (const float*)d_in[4];
    const float* bk  = (const float*)d_in[5];
    const float* Wv  = (const float*)d_in[6];
    const float* bv  = (const float*)d_in[7];
    const float* Wo  = (const float*)d_in[8];
    const float* bo  = (const float*)d_in[9];
    const float* Wfp = (const float*)d_in[10];
    const float* bfp = (const float*)d_in[11];
    float* out = (float*)d_out;

    char* ws = (char*)d_ws;
    float* gate = (float*)(ws);                                      // 64 KB
    unsigned short* Qb = (unsigned short*)(ws + 65536);              // 2 MB
    unsigned short* Kb = (unsigned short*)(ws + 65536 + 2097152);    // 2 MB
    unsigned short* Vb = (unsigned short*)(ws + 65536 + 2 * 2097152);// 2 MB
    unsigned short* Opart = (unsigned short*)(ws + 65536 + 3 * 2097152); // 16 MB bf16 (8 splits)
    float* lpart = (float*)(ws + 65536 + 3 * 2097152 + 16777216);    // 512 KB

    // no memset needed: every Opart/lpart element is written exactly once

    hipLaunchKernelGGL(qkv_kernel, dim3(768), dim3(256), 0, stream,
                       x, Wq, bq, Wk, bk, Wv, bv, fp, Wfp, bfp,
                       gate, Qb, Kb, Vb);
    hipLaunchKernelGGL(attn_kernel, dim3(1024), dim3(256), 0, stream,
                       Qb, Kb, Vb, Opart, lpart);
    hipLaunchKernelGGL(epi_kernel, dim3(512), dim3(256), 0, stream,
                       Opart, lpart, x, gate, Wo, bo, out);
}